// Round 18
// baseline (150.460 us; speedup 1.0000x reference)
//
#include <hip/hip_runtime.h>
#include <math.h>

#define NBLK 512
#define EPS32 1.1920928955078125e-07

// agent-scope atomics: always at the coherent point (LLC)
__device__ __forceinline__ double ld_acc(const double* p){
  return __hip_atomic_load(p, __ATOMIC_RELAXED, __HIP_MEMORY_SCOPE_AGENT);
}
__device__ __forceinline__ unsigned ld_u32(const unsigned* p){
  return __hip_atomic_load(p, __ATOMIC_RELAXED, __HIP_MEMORY_SCOPE_AGENT);
}
__device__ __forceinline__ void st_u32(unsigned* p, unsigned v){
  __hip_atomic_store(p, v, __ATOMIC_RELAXED, __HIP_MEMORY_SCOPE_AGENT);
}

// ---- r18 FLAT sync: 64 leaves (8 blocks each, relaxed) -> root (64 RMWs,
// relaxed). No mid/fold level (r17's fold cost ~2-3 dependent LLC trips).
// Correctness by completion-ordering: a block's deposits COMPLETE before its
// leaf RMW (caller's __syncthreads drains vmcnt); a leaf-last's root RMW is
// issued only after its leaf's 8 RMWs completed; root==64 => all 512 blocks'
// deposits are visible. Root-last gathers all 16 deposit shards directly
// (144 pipelined loads ~2 trips), computes omega once, publishes 8 replicated
// rec lines (payloads, then release-stored flags). Pollers: flag -> payload
// (r14-proven). tid0-only.
__device__ void flat_sync_omega(unsigned* leafL, unsigned* rootL,
                                unsigned* recL, const double* accsG,
                                float* somf, int l6, int g3){
  unsigned o = __hip_atomic_fetch_add(leafL + (size_t)l6 * 32, 1u,
                                      __ATOMIC_RELAXED, __HIP_MEMORY_SCOPE_AGENT);
  if (o == 7u){
    unsigned orr = __hip_atomic_fetch_add(rootL, 1u,
                                          __ATOMIC_RELAXED, __HIP_MEMORY_SCOPE_AGENT);
    if (orr == 63u){                          // global last: gather + publish
      double s0=0, s1=0, s2=0, s3=0, s4=0, s5=0, s6=0, s7=0, s8=0;
      #pragma unroll
      for (int s = 0; s < 16; ++s){
        const double* ag = accsG + (size_t)s * 16;
        s0 += ld_acc(ag+0); s1 += ld_acc(ag+1); s2 += ld_acc(ag+2);
        s3 += ld_acc(ag+3); s4 += ld_acc(ag+4); s5 += ld_acc(ag+5);
        s6 += ld_acc(ag+6); s7 += ld_acc(ag+7); s8 += ld_acc(ag+8);
      }
      float o0 = (float)(s0 / s4);
      float o1 = (float)(s1 / s5);
      float o2 = (float)(s2 / s6);
      float o3 = (float)(s3 / s7);
      unsigned fl = (s8 * (1.0 / 4096.0) + EPS32 > 5e-5) ? 3u : 1u;
      #pragma unroll
      for (int r = 0; r < 8; ++r){
        unsigned* rl = recL + (size_t)r * 32;
        st_u32(rl + 1, __float_as_uint(o0));
        st_u32(rl + 2, __float_as_uint(o1));
        st_u32(rl + 3, __float_as_uint(o2));
        st_u32(rl + 4, __float_as_uint(o3));
      }
      #pragma unroll
      for (int r = 0; r < 8; ++r)             // release: payloads before flags
        __hip_atomic_store(recL + (size_t)r * 32, fl,
                           __ATOMIC_RELEASE, __HIP_MEMORY_SCOPE_AGENT);
    }
  }
  unsigned* myrec = recL + (size_t)g3 * 32;
  unsigned f, spins = 0;
  while (((f = ld_u32(myrec)) & 1u) == 0u){
    if (++spins > (1u << 22)) break;          // safety valve: fail loud, not hung
    __builtin_amdgcn_s_sleep(1);
  }
  somf[7] = (f & 2u) ? 1.f : 0.f;
  somf[0] = __uint_as_float(ld_u32(myrec + 1));
  somf[1] = __uint_as_float(ld_u32(myrec + 2));
  somf[2] = __uint_as_float(ld_u32(myrec + 3));
  somf[3] = __uint_as_float(ld_u32(myrec + 4));
}

// ---- radix-4 register butterfly ----
#define R4REG(A, B, C, D, W1, W2, W3, SGN, Y0, Y1, Y2, Y3) {    \
  float w1y_ = (SGN)*W1.y, w2y_ = (SGN)*W2.y, w3y_ = (SGN)*W3.y;\
  float t0x = A.x + C.x, t0y = A.y + C.y;                       \
  float t1x = A.x - C.x, t1y = A.y - C.y;                       \
  float t2x = B.x + D.x, t2y = B.y + D.y;                       \
  float t3x = (SGN) * (B.y - D.y), t3y = -(SGN) * (B.x - D.x);  \
  Y0 = make_float2(t0x + t2x, t0y + t2y);                       \
  float y1x = t1x + t3x, y1y = t1y + t3y;                       \
  float y2x = t0x - t2x, y2y = t0y - t2y;                       \
  float y3x = t1x - t3x, y3y = t1y - t3y;                       \
  Y1 = make_float2(y1x*W1.x - y1y*w1y_, y1x*w1y_ + y1y*W1.x);   \
  Y2 = make_float2(y2x*W2.x - y2y*w2y_, y2x*w2y_ + y2y*W2.x);   \
  Y3 = make_float2(y3x*W3.x - y3y*w3y_, y3x*w3y_ + y3y*W3.x); }

// ---- 1024-pt Stockham radix-4 LDS stages; L = 4<<(2t); 1 bf/thread.
//      `unroll 1` (r6 spill lesson). twl = W_1024 table (768 entries). ----
__device__ __forceinline__ void r4s(float2* src, float2* dst,
                                    const float2* twl, float sgn, int cnt){
  const int tid = threadIdx.x;
  #pragma unroll 1
  for (int t = 0; t < cnt; ++t){
    const int L = 4 << (2 * t);
    const int Lm = L - 1;
    int q  = tid & Lm;
    int tb = tid - q;                         // p*L
    float2 a = src[tid];
    float2 b = src[tid + 256];
    float2 c = src[tid + 512];
    float2 d = src[tid + 768];
    float2 w1 = twl[tb];
    float2 w2 = twl[2 * tb];
    float2 w3 = twl[3 * tb];
    float2 y0, y1, y2, y3;
    R4REG(a, b, c, d, w1, w2, w3, sgn, y0, y1, y2, y3)
    int ob = q + (tb << 2);                   // q + 4*p*L
    dst[ob]         = y0;
    dst[ob + L]     = y1;
    dst[ob + 2 * L] = y2;
    dst[ob + 3 * L] = y3;
    __syncthreads();
    float2* tt = src; src = dst; dst = tt;
  }
}

// ---- wave-64 shuffle sum (f32 partials, 8-bin coverage -> exact enough) ----
__device__ __forceinline__ float wredf(float v){
  #pragma unroll
  for (int off = 32; off; off >>= 1) v += __shfl_down(v, off);
  return v;
}

// ---- reduce 9 f32 partials -> f64 atomicAdd into this round's shard ----
__device__ __forceinline__ void red9(float a0, float a1, float a2, float a3,
                                     float a4, float a5, float a6, float a7,
                                     float a8, float* redf, double* shard){
  const int tid = threadIdx.x, wave = tid >> 6, lane = tid & 63;
  float r;
  r = wredf(a0); if (lane == 0) redf[ 0 + wave] = r;
  r = wredf(a1); if (lane == 0) redf[ 4 + wave] = r;
  r = wredf(a2); if (lane == 0) redf[ 8 + wave] = r;
  r = wredf(a3); if (lane == 0) redf[12 + wave] = r;
  r = wredf(a4); if (lane == 0) redf[16 + wave] = r;
  r = wredf(a5); if (lane == 0) redf[20 + wave] = r;
  r = wredf(a6); if (lane == 0) redf[24 + wave] = r;
  r = wredf(a7); if (lane == 0) redf[28 + wave] = r;
  r = wredf(a8); if (lane == 0) redf[32 + wave] = r;
  __syncthreads();
  if (tid < 9){
    double s = (double)redf[tid*4+0] + (double)redf[tid*4+1]
             + (double)redf[tid*4+2] + (double)redf[tid*4+3];
    atomicAdd(&shard[tid], s);
  }
}

// ---- REAL mode update (r16): ~10 ops/mode, rcp divide (r15) ----
#define MODE_R(RC, OMC, AFP, AP) {                             \
  float o_ = s - (RC);                                         \
  float d_ = fj - (OMC);                                       \
  float rd_ = __builtin_amdgcn_rcpf(fmaf(2000.0f*d_, d_, 1.0f));\
  float n_ = (RR - o_) * rd_;                                  \
  float pw_ = n_ * n_;                                         \
  AFP += fj * pw_;  AP += pw_;                                 \
  float dd_ = n_ - (RC);  aD += dd_ * dd_;                     \
  (RC) = n_;  s = o_ + n_; }

#define RBIN(RHO, RRv, FJ) {                                   \
  float RR = RRv;  float fj = FJ;                              \
  float s = RHO.x + RHO.y + RHO.z + RHO.w;                     \
  MODE_R(RHO.x, om.x, aFP0, aP0)                               \
  MODE_R(RHO.y, om.y, aFP1, aP1)                               \
  MODE_R(RHO.z, om.z, aFP2, aP2)                               \
  MODE_R(RHO.w, om.w, aFP3, aP3) }

#define IT1R(RHO, RRv, FJ) { RHO = make_float4(0.f,0.f,0.f,0.f); RBIN(RHO, RRv, FJ) }

#define FOR8R(M) M(r0,R0,fj0) M(r1,R1,fj1) M(r2,R2,fj2) M(r3,R3,fj3) \
                 M(r4,R4,fj4) M(r5,R5,fj5) M(r6,R6,fj6) M(r7,R7,fj7)

// iter-5 mode-0 update (real), guarded
#define C5(RHO, RRv, FJ, CV) {                                 \
  if (act){                                                    \
    float o_ = RHO.y + RHO.z + RHO.w;                          \
    float d_ = FJ - om0;                                       \
    float rd_ = __builtin_amdgcn_rcpf(fmaf(2000.0f*d_, d_, 1.0f));\
    CV = (RRv - o_) * rd_;                                     \
  } else CV = RHO.x; }

// ==== r18 = r16/r17 real-domain pipeline + flat 2-level sync (no fold) +
// 16-way deposit shards. ====
__global__ void __attribute__((amdgpu_flat_work_group_size(256, 256),
                               amdgpu_waves_per_eu(2, 2)))
k_main(const float* __restrict__ x, unsigned* __restrict__ leaf,
       unsigned* __restrict__ root, unsigned* __restrict__ rec,
       double* __restrict__ accs, float* __restrict__ xh, float* __restrict__ xl){
  __shared__ float2 twl[768];                 // W_1024 table (6 KiB)
  __shared__ float2 bufA[1024];               // 8 KiB
  __shared__ float2 bufB[1024];               // 8 KiB
  __shared__ float redf[36];
  __shared__ float somf[8];
  __shared__ float2 vNy;                      // V'[1024]
  __shared__ float sKs;                       // c_2047 broadcast
  const int tid = threadIdx.x;
  const int b = blockIdx.x & 7, ch = blockIdx.x >> 3;
  const int l6 = blockIdx.x & 63, g3 = blockIdx.x & 7, g4 = blockIdx.x & 15;
  const float* xc = x + (size_t)b * 2048 * 64 + ch;

  // ---- twiddles W_1024^p, p=0..767 (3/thread; rev = -p/1024 exact) ----
  #pragma unroll
  for (int i = 0; i < 3; ++i){
    int p = tid + (i << 8);
    float rev = (float)p * (-1.0f / 1024.0f);
    twl[p] = make_float2(__builtin_amdgcn_cosf(rev), __builtin_amdgcn_sinf(rev));
  }

  // ---- load f via DCT even/odd permute+pack (za..zd double as output stash) ----
  float2 za = make_float2(xc[(size_t)(4*tid       ) * 64], xc[(size_t)(4*tid + 2   ) * 64]);
  float2 zb = make_float2(xc[(size_t)(4*tid + 1024) * 64], xc[(size_t)(4*tid + 1026) * 64]);
  float2 zc = make_float2(xc[(size_t)(2047 - 4*tid) * 64], xc[(size_t)(2045 - 4*tid) * 64]);
  float2 zd = make_float2(xc[(size_t)(1023 - 4*tid) * 64], xc[(size_t)(1021 - 4*tid) * 64]);
  __syncthreads();                            // twl visible

  // ---- forward 1024-pt FFT: fused radix-4 L=1 (regs) + 3 LDS stages +
  //      fused last stage (L=256, tb=0, twiddle-free) kept in registers ----
  {
    float2 w1 = twl[tid], w2 = twl[2*tid], w3 = twl[3*tid];
    float2 y0, y1, y2, y3;
    R4REG(za, zb, zc, zd, w1, w2, w3, 1.0f, y0, y1, y2, y3)
    float4* d4 = reinterpret_cast<float4*>(bufA + 4 * tid);
    d4[0] = make_float4(y0.x, y0.y, y1.x, y1.y);
    d4[1] = make_float4(y2.x, y2.y, y3.x, y3.y);
  }
  __syncthreads();
  r4s(bufA, bufB, twl, 1.0f, 3);              // L=4,16,64 -> result in bufB
  float2 Zs0, Zs1, Zs2, Zs3;                  // Z[tid + {0,256,512,768}]
  {
    float2 a = bufB[tid], b2 = bufB[tid + 256];
    float2 c2 = bufB[tid + 512], d2 = bufB[tid + 768];
    float t0x = a.x + c2.x, t0y = a.y + c2.y;
    float t1x = a.x - c2.x, t1y = a.y - c2.y;
    float t2x = b2.x + d2.x, t2y = b2.y + d2.y;
    float t3x = (b2.y - d2.y), t3y = -(b2.x - d2.x);   // fwd -i*(b-d)
    Zs0 = make_float2(t0x + t2x, t0y + t2y);
    Zs1 = make_float2(t1x + t3x, t1y + t3y);
    Zs2 = make_float2(t0x - t2x, t0y - t2y);
    Zs3 = make_float2(t1x - t3x, t1y - t3y);
    bufA[tid]       = Zs0;  bufA[tid + 256] = Zs1;
    bufA[tid + 512] = Zs2;  bufA[tid + 768] = Zs3;
  }
  __syncthreads();

  // ---- unpack: per c, bins (k, 2048-k): R = 2C; own Z from regs ----
  float R0,R1,R2,R3,R4,R5,R6,R7, fj0,fj1,fj2,fj3,fj4,fj5,fj6,fj7;
  #define UNPK(C, ZS, RA, RB, FA, FB) {                        \
    int k = tid + ((C) << 8);                                  \
    float2 Zk = ZS;                                            \
    float2 Zm = bufA[(1024 - k) & 1023];                       \
    float px = 0.5f*(Zk.x + Zm.x), py = 0.5f*(Zk.y - Zm.y);    \
    float qx = 0.5f*(Zk.x - Zm.x), qy = 0.5f*(Zk.y + Zm.y);    \
    float rw = (float)k * (-1.0f / 2048.0f);                   \
    float Wx = __builtin_amdgcn_cosf(rw), Wy = __builtin_amdgcn_sinf(rw); \
    float Vx = px + Wx*qy + Wy*qx;                             \
    float Vy = py - Wx*qx + Wy*qy;                             \
    float re = (float)k * (-1.0f / 8192.0f);                   \
    float Ex = __builtin_amdgcn_cosf(re), Ey = __builtin_amdgcn_sinf(re); \
    RA = 2.0f * (Ex*Vx - Ey*Vy);                               \
    RB = -2.0f * (Ex*Vy + Ey*Vx);                              \
    FA = (float)k * (1.0f/4096.0f);                            \
    FB = (float)(2048 - k) * (1.0f/4096.0f); }
  UNPK(0, Zs0, R0, R1, fj0, fj1)
  UNPK(1, Zs1, R2, R3, fj2, fj3)
  UNPK(2, Zs2, R4, R5, fj4, fj5)
  UNPK(3, Zs3, R6, R7, fj6, fj7)
  if (tid == 0){                              // k=0 pair is (bin0, bin1024)
    R1 = 1.41421356237f * (Zs0.x - Zs0.y);    // sqrt2*V[1024]
    fj1 = 0.25f;
  }

  float4 r0, r1, r2, r3, r4, r5, r6, r7;      // rho[mode] per bin
  float4 om = make_float4(0.0f, 0.125f, 0.25f, 0.375f);

  // iter 1 (rho starts 0) — pure register, real
  {
    float aFP0=0,aFP1=0,aFP2=0,aFP3=0,aP0=0,aP1=0,aP2=0,aP3=0,aD=0;
    FOR8R(IT1R)
    red9(aFP0,aFP1,aFP2,aFP3,aP0,aP1,aP2,aP3,aD, redf, accs + (size_t)g4*16);
  }

  // ---- iters 2..4: flat sync + replicated-record omega ----
  bool active = true;
  #pragma unroll 1
  for (int it = 0; it < 3; ++it){
    __syncthreads();                          // drain this block's deposits
    if (tid == 0)
      flat_sync_omega(leaf + (size_t)it*64*32, root + (size_t)it*32,
                      rec + (size_t)it*8*32, accs + (size_t)it*256,
                      somf, l6, g3);
    __syncthreads();                          // somf visible to all
    if (active){
      if (somf[7] != 0.0f){
        om.x = somf[0]; om.y = somf[1]; om.z = somf[2]; om.w = somf[3];
      } else active = false;
    }
    if (active){
      float aFP0=0,aFP1=0,aFP2=0,aFP3=0,aP0=0,aP1=0,aP2=0,aP3=0,aD=0;
      FOR8R(RBIN)
      red9(aFP0,aFP1,aFP2,aFP3,aP0,aP1,aP2,aP3,aD, redf,
           accs + (size_t)(it + 1)*256 + (size_t)g4*16);
    }
  }
  __syncthreads();
  if (tid == 0)
    flat_sync_omega(leaf + (size_t)3*64*32, root + (size_t)3*32,
                    rec + (size_t)3*8*32, accs + (size_t)3*256,
                    somf, l6, g3);
  __syncthreads();

  // ---- iter-5 mode-0 (real) -> c values; V' -> bufA; packed IFFT ----
  {
    bool act = active && (somf[7] != 0.0f);
    float om0 = somf[0];
    float c0, c1, c2, c3, c4, c5, c6, c7;
    C5(r0, R0, fj0, c0)  C5(r1, R1, fj1, c1)
    C5(r2, R2, fj2, c2)  C5(r3, R3, fj3, c3)
    C5(r4, R4, fj4, c4)  C5(r5, R5, fj5, c5)
    C5(r6, R6, fj6, c6)  C5(r7, R7, fj7, c7)
    if (tid == 1) sKs = c1;                   // bin 2047 (pair of k=1)
    if (tid == 0) vNy = make_float2(1.41421356237f * c1, 0.0f); // V'[1024]
    // V'[k] = e^{+i pi k/4096} (c_k - i c_{2048-k})
    #define VPW(C, CA, CB) {                                   \
      int k = tid + ((C) << 8);                                \
      float rg = (float)k * (1.0f / 8192.0f);                  \
      float Gx = __builtin_amdgcn_cosf(rg), Gy = __builtin_amdgcn_sinf(rg); \
      bufA[k] = make_float2(Gx*(CA) + Gy*(CB), Gy*(CA) - Gx*(CB)); }
    VPW(0, c0, c1)  VPW(1, c2, c3)  VPW(2, c4, c5)  VPW(3, c6, c7)
    if (tid == 0) bufA[0] = make_float2(c0, 0.0f);   // V'[0] = c_0 (real)
  }
  __syncthreads();
  // Z''[q] = E + iO; E = V'[q]+conj(V'[1024-q]); O = (V'[q]-conj(V'[1024-q]))*W
  float2 p0, p1, p2, p3;
  #define ZB(C, ZV) {                                          \
    int q = tid + ((C) << 8);                                  \
    float2 Vq = bufA[q];                                       \
    float2 Vm = (q == 0) ? vNy : bufA[1024 - q];               \
    Vm.y = -Vm.y;                                              \
    float Ex_ = Vq.x + Vm.x, Ey_ = Vq.y + Vm.y;                \
    float Dx = Vq.x - Vm.x,  Dy = Vq.y - Vm.y;                 \
    float rw = (float)q * (1.0f / 2048.0f);                    \
    float Wx = __builtin_amdgcn_cosf(rw), Wy = __builtin_amdgcn_sinf(rw); \
    float Ox = Dx*Wx - Dy*Wy;                                  \
    float Oy = Dx*Wy + Dy*Wx;                                  \
    ZV = make_float2(Ex_ - Oy, Ey_ + Ox); }
  ZB(0, p0)  ZB(1, p1)  ZB(2, p2)  ZB(3, p3)
  {                                           // fused inverse radix-4 L=1
    float2 w1 = twl[tid], w2 = twl[2*tid], w3 = twl[3*tid];
    float2 y0, y1, y2, y3;
    R4REG(p0, p1, p2, p3, w1, w2, w3, -1.0f, y0, y1, y2, y3)
    float4* d4 = reinterpret_cast<float4*>(bufB + 4 * tid);
    d4[0] = make_float4(y0.x, y0.y, y1.x, y1.y);
    d4[1] = make_float4(y2.x, y2.y, y3.x, y3.y);
  }
  __syncthreads();
  r4s(bufB, bufA, twl, -1.0f, 3);             // L=4,16,64 -> result in bufA

  // ---- fused last inverse stage (L=256, tb=0, twiddle-free) + epilogue ----
  {
    float2 a = bufA[tid], bb = bufA[tid + 256];
    float2 c = bufA[tid + 512], d = bufA[tid + 768];
    float t0x = a.x + c.x, t0y = a.y + c.y;
    float t1x = a.x - c.x, t1y = a.y - c.y;
    float t2x = bb.x + d.x, t2y = bb.y + d.y;
    float t3x = -(bb.y - d.y), t3y = (bb.x - d.x);   // sgn=-1
    float2 y0 = make_float2(t0x + t2x, t0y + t2y);   // z''[tid]
    float2 y1 = make_float2(t1x + t3x, t1y + t3y);   // z''[tid+256]
    float2 y2 = make_float2(t0x - t2x, t0y - t2y);   // z''[tid+512]
    float2 y3 = make_float2(t1x - t3x, t1y - t3y);   // z''[tid+768]
    const float sc = 1.0f / 4096.0f;
    float kc = sKs * (0.99999970586f * sc);   // rho_2047*cos(pi/4096)/4096
    // x_l[t] = Re(z'')/4096 - (-1)^t * kc
    #define OUT2(YV, T0, T1, KS, ZS) {                         \
      size_t oa = ((size_t)(b * 2048 + (T0))) * 64 + ch;       \
      size_t ob = ((size_t)(b * 2048 + (T1))) * 64 + ch;       \
      float l0 = YV.x * sc KS kc;                              \
      float l1 = YV.y * sc KS kc;                              \
      xl[oa] = l0;  xh[oa] = ZS.x - l0;                        \
      xl[ob] = l1;  xh[ob] = ZS.y - l1; }
    OUT2(y0, 4*tid,        4*tid + 2,    -, za)      // even t
    OUT2(y1, 4*tid + 1024, 4*tid + 1026, -, zb)      // even t
    OUT2(y2, 2047 - 4*tid, 2045 - 4*tid, +, zc)      // odd t
    OUT2(y3, 1023 - 4*tid, 1021 - 4*tid, +, zd)      // odd t
  }
}

extern "C" void kernel_launch(void* const* d_in, const int* in_sizes, int n_in,
                              void* d_out, int out_size, void* d_ws, size_t ws_size,
                              hipStream_t stream){
  const float* x = (const float*)d_in[0];
  float* out_xh = (float*)d_out;
  float* out_xl = out_xh + (size_t)8 * 2048 * 64;

  // ws layout (all zeroed each launch; 128-B lines):
  //   leaf: 4 rounds x 64 x 128B = 32768 @ 0
  //   root: 4 x 128B             =   512 @ 32768
  //   rec:  4 x 8 x 128B         =  4096 @ 33280
  //   accs: 4 x 16 x 128B        =  8192 @ 37376
  char* ws = (char*)d_ws;
  unsigned* leaf = (unsigned*)ws;
  unsigned* root = (unsigned*)(ws + 32768);
  unsigned* rec  = (unsigned*)(ws + 33280);
  double*   accs = (double*)  (ws + 37376);

  hipMemsetAsync(ws, 0, 45568, stream);
  k_main<<<NBLK, 256, 0, stream>>>(x, leaf, root, rec, accs, out_xh, out_xl);
}

// Round 19
// 111.572 us; speedup vs baseline: 1.3485x; 1.3485x over previous
//
#include <hip/hip_runtime.h>
#include <math.h>

#define NBLK 512
#define EPS32 1.1920928955078125e-07

// agent-scope atomics: always at the coherent point (LLC)
__device__ __forceinline__ double ld_acc(const double* p){
  return __hip_atomic_load(p, __ATOMIC_RELAXED, __HIP_MEMORY_SCOPE_AGENT);
}
__device__ __forceinline__ unsigned ld_u32(const unsigned* p){
  return __hip_atomic_load(p, __ATOMIC_RELAXED, __HIP_MEMORY_SCOPE_AGENT);
}
__device__ __forceinline__ void st_u32(unsigned* p, unsigned v){
  __hip_atomic_store(p, v, __ATOMIC_RELAXED, __HIP_MEMORY_SCOPE_AGENT);
}

// ---- r17 sync fabric (PROVEN BEST of 3 designs: r14 coarse tree 81us,
// r18 flat 101us, r17 64.5us). Arrival: 64 leaves (8 blocks) -> 8 mids ->
// root; max 8 same-line RMWs AT EVERY LEVEL (r18 lesson: a 64-deep same-line
// RMW queue on the root costs ~6us/round). Deposits sharded into accs[g3]
// (8 lines). Mid-last FOLDS its shard into racc (9 adds) and bumps root with
// ACQ_REL (release orders folds; acquire on root-last makes them visible).
// Root-last reads racc only, computes omega once, publishes 8 replicated rec
// lines; each block polls its g3 line (64 pollers/line). tid0-only; caller's
// __syncthreads drains this block's deposits before arrival.
__device__ void tree_sync_omega(unsigned* leafL, unsigned* midL, unsigned* rootL,
                                unsigned* recL, const double* accsG,
                                double* racc, float* somf, int l6, int g3){
  unsigned o = __hip_atomic_fetch_add(leafL + (size_t)l6 * 32, 1u,
                                      __ATOMIC_RELAXED, __HIP_MEMORY_SCOPE_AGENT);
  if (o == 7u){
    int m = l6 & 7;
    unsigned om_ = __hip_atomic_fetch_add(midL + (size_t)m * 32, 1u,
                                          __ATOMIC_RELAXED, __HIP_MEMORY_SCOPE_AGENT);
    if (om_ == 7u){                           // mid-last: fold shard m
      const double* ag = accsG + (size_t)m * 16;
      double v0 = ld_acc(ag+0), v1 = ld_acc(ag+1), v2 = ld_acc(ag+2);
      double v3 = ld_acc(ag+3), v4 = ld_acc(ag+4), v5 = ld_acc(ag+5);
      double v6 = ld_acc(ag+6), v7 = ld_acc(ag+7), v8 = ld_acc(ag+8);
      atomicAdd(racc+0, v0); atomicAdd(racc+1, v1); atomicAdd(racc+2, v2);
      atomicAdd(racc+3, v3); atomicAdd(racc+4, v4); atomicAdd(racc+5, v5);
      atomicAdd(racc+6, v6); atomicAdd(racc+7, v7); atomicAdd(racc+8, v8);
      unsigned orr = __hip_atomic_fetch_add(rootL, 1u,
                                            __ATOMIC_ACQ_REL, __HIP_MEMORY_SCOPE_AGENT);
      if (orr == 7u){                         // root-last: compute + publish x8
        double uD = ld_acc(racc + 8);
        float o0 = (float)(ld_acc(racc+0) / ld_acc(racc+4));
        float o1 = (float)(ld_acc(racc+1) / ld_acc(racc+5));
        float o2 = (float)(ld_acc(racc+2) / ld_acc(racc+6));
        float o3 = (float)(ld_acc(racc+3) / ld_acc(racc+7));
        unsigned fl = (uD * (1.0 / 4096.0) + EPS32 > 5e-5) ? 3u : 1u;
        #pragma unroll
        for (int r = 0; r < 8; ++r){
          unsigned* rl = recL + (size_t)r * 32;
          st_u32(rl + 1, __float_as_uint(o0));
          st_u32(rl + 2, __float_as_uint(o1));
          st_u32(rl + 3, __float_as_uint(o2));
          st_u32(rl + 4, __float_as_uint(o3));
        }
        #pragma unroll
        for (int r = 0; r < 8; ++r)           // release: payloads before flags
          __hip_atomic_store(recL + (size_t)r * 32, fl,
                             __ATOMIC_RELEASE, __HIP_MEMORY_SCOPE_AGENT);
      }
    }
  }
  unsigned* myrec = recL + (size_t)g3 * 32;
  unsigned f, spins = 0;
  while (((f = ld_u32(myrec)) & 1u) == 0u){
    if (++spins > (1u << 22)) break;          // safety valve: fail loud, not hung
    __builtin_amdgcn_s_sleep(1);
  }
  somf[7] = (f & 2u) ? 1.f : 0.f;
  somf[0] = __uint_as_float(ld_u32(myrec + 1));  // issued after flag returns;
  somf[1] = __uint_as_float(ld_u32(myrec + 2));  // writer's release ordered
  somf[2] = __uint_as_float(ld_u32(myrec + 3));  // payloads first (r14-proven)
  somf[3] = __uint_as_float(ld_u32(myrec + 4));
}

// ---- radix-4 register butterfly ----
#define R4REG(A, B, C, D, W1, W2, W3, SGN, Y0, Y1, Y2, Y3) {    \
  float w1y_ = (SGN)*W1.y, w2y_ = (SGN)*W2.y, w3y_ = (SGN)*W3.y;\
  float t0x = A.x + C.x, t0y = A.y + C.y;                       \
  float t1x = A.x - C.x, t1y = A.y - C.y;                       \
  float t2x = B.x + D.x, t2y = B.y + D.y;                       \
  float t3x = (SGN) * (B.y - D.y), t3y = -(SGN) * (B.x - D.x);  \
  Y0 = make_float2(t0x + t2x, t0y + t2y);                       \
  float y1x = t1x + t3x, y1y = t1y + t3y;                       \
  float y2x = t0x - t2x, y2y = t0y - t2y;                       \
  float y3x = t1x - t3x, y3y = t1y - t3y;                       \
  Y1 = make_float2(y1x*W1.x - y1y*w1y_, y1x*w1y_ + y1y*W1.x);   \
  Y2 = make_float2(y2x*W2.x - y2y*w2y_, y2x*w2y_ + y2y*W2.x);   \
  Y3 = make_float2(y3x*W3.x - y3y*w3y_, y3x*w3y_ + y3y*W3.x); }

// ---- 1024-pt Stockham radix-4 LDS stages; L = 4<<(2t); 1 bf/thread.
//      `unroll 1` (r6 spill lesson). twl = W_1024 table (768 entries). ----
__device__ __forceinline__ void r4s(float2* src, float2* dst,
                                    const float2* twl, float sgn, int cnt){
  const int tid = threadIdx.x;
  #pragma unroll 1
  for (int t = 0; t < cnt; ++t){
    const int L = 4 << (2 * t);
    const int Lm = L - 1;
    int q  = tid & Lm;
    int tb = tid - q;                         // p*L
    float2 a = src[tid];
    float2 b = src[tid + 256];
    float2 c = src[tid + 512];
    float2 d = src[tid + 768];
    float2 w1 = twl[tb];
    float2 w2 = twl[2 * tb];
    float2 w3 = twl[3 * tb];
    float2 y0, y1, y2, y3;
    R4REG(a, b, c, d, w1, w2, w3, sgn, y0, y1, y2, y3)
    int ob = q + (tb << 2);                   // q + 4*p*L
    dst[ob]         = y0;
    dst[ob + L]     = y1;
    dst[ob + 2 * L] = y2;
    dst[ob + 3 * L] = y3;
    __syncthreads();
    float2* tt = src; src = dst; dst = tt;
  }
}

// ---- wave-64 shuffle sum (f32 partials, 8-bin coverage -> exact enough) ----
__device__ __forceinline__ float wredf(float v){
  #pragma unroll
  for (int off = 32; off; off >>= 1) v += __shfl_down(v, off);
  return v;
}

// ---- reduce 9 f32 partials -> f64 atomicAdd into this round's gid shard ----
__device__ __forceinline__ void red9(float a0, float a1, float a2, float a3,
                                     float a4, float a5, float a6, float a7,
                                     float a8, float* redf, double* accsG){
  const int tid = threadIdx.x, wave = tid >> 6, lane = tid & 63;
  float r;
  r = wredf(a0); if (lane == 0) redf[ 0 + wave] = r;
  r = wredf(a1); if (lane == 0) redf[ 4 + wave] = r;
  r = wredf(a2); if (lane == 0) redf[ 8 + wave] = r;
  r = wredf(a3); if (lane == 0) redf[12 + wave] = r;
  r = wredf(a4); if (lane == 0) redf[16 + wave] = r;
  r = wredf(a5); if (lane == 0) redf[20 + wave] = r;
  r = wredf(a6); if (lane == 0) redf[24 + wave] = r;
  r = wredf(a7); if (lane == 0) redf[28 + wave] = r;
  r = wredf(a8); if (lane == 0) redf[32 + wave] = r;
  __syncthreads();
  if (tid < 9){
    double s = (double)redf[tid*4+0] + (double)redf[tid*4+1]
             + (double)redf[tid*4+2] + (double)redf[tid*4+3];
    atomicAdd(&accsG[tid], s);
  }
}

// ---- REAL mode update (r16): ~10 ops/mode, rcp divide (r15) ----
#define MODE_R(RC, OMC, AFP, AP) {                             \
  float o_ = s - (RC);                                         \
  float d_ = fj - (OMC);                                       \
  float rd_ = __builtin_amdgcn_rcpf(fmaf(2000.0f*d_, d_, 1.0f));\
  float n_ = (RR - o_) * rd_;                                  \
  float pw_ = n_ * n_;                                         \
  AFP += fj * pw_;  AP += pw_;                                 \
  float dd_ = n_ - (RC);  aD += dd_ * dd_;                     \
  (RC) = n_;  s = o_ + n_; }

#define RBIN(RHO, RRv, FJ) {                                   \
  float RR = RRv;  float fj = FJ;                              \
  float s = RHO.x + RHO.y + RHO.z + RHO.w;                     \
  MODE_R(RHO.x, om.x, aFP0, aP0)                               \
  MODE_R(RHO.y, om.y, aFP1, aP1)                               \
  MODE_R(RHO.z, om.z, aFP2, aP2)                               \
  MODE_R(RHO.w, om.w, aFP3, aP3) }

#define IT1R(RHO, RRv, FJ) { RHO = make_float4(0.f,0.f,0.f,0.f); RBIN(RHO, RRv, FJ) }

#define FOR8R(M) M(r0,R0,fj0) M(r1,R1,fj1) M(r2,R2,fj2) M(r3,R3,fj3) \
                 M(r4,R4,fj4) M(r5,R5,fj5) M(r6,R6,fj6) M(r7,R7,fj7)

// iter-5 mode-0 update (real), guarded
#define C5(RHO, RRv, FJ, CV) {                                 \
  if (act){                                                    \
    float o_ = RHO.y + RHO.z + RHO.w;                          \
    float d_ = FJ - om0;                                       \
    float rd_ = __builtin_amdgcn_rcpf(fmaf(2000.0f*d_, d_, 1.0f));\
    CV = (RRv - o_) * rd_;                                     \
  } else CV = RHO.x; }

// ==== r19 = exact revert to r17 (proven 64.5us steady / 113us total; r18's
// flat-sync variant regressed to 101us steady — 64-deep root RMW queue). ====
__global__ void __attribute__((amdgpu_flat_work_group_size(256, 256),
                               amdgpu_waves_per_eu(2, 2)))
k_main(const float* __restrict__ x, unsigned* __restrict__ leaf,
       unsigned* __restrict__ mid, unsigned* __restrict__ root,
       unsigned* __restrict__ rec, double* __restrict__ racc,
       double* __restrict__ accs, float* __restrict__ xh, float* __restrict__ xl){
  __shared__ float2 twl[768];                 // W_1024 table (6 KiB)
  __shared__ float2 bufA[1024];               // 8 KiB
  __shared__ float2 bufB[1024];               // 8 KiB
  __shared__ float redf[36];
  __shared__ float somf[8];
  __shared__ float2 vNy;                      // V'[1024]
  __shared__ float sKs;                       // c_2047 broadcast
  const int tid = threadIdx.x;
  const int b = blockIdx.x & 7, ch = blockIdx.x >> 3;
  const int l6 = blockIdx.x & 63, g3 = blockIdx.x & 7;
  const float* xc = x + (size_t)b * 2048 * 64 + ch;

  // ---- twiddles W_1024^p, p=0..767 (3/thread; rev = -p/1024 exact) ----
  #pragma unroll
  for (int i = 0; i < 3; ++i){
    int p = tid + (i << 8);
    float rev = (float)p * (-1.0f / 1024.0f);
    twl[p] = make_float2(__builtin_amdgcn_cosf(rev), __builtin_amdgcn_sinf(rev));
  }

  // ---- load f via DCT even/odd permute+pack (za..zd double as output stash) ----
  float2 za = make_float2(xc[(size_t)(4*tid       ) * 64], xc[(size_t)(4*tid + 2   ) * 64]);
  float2 zb = make_float2(xc[(size_t)(4*tid + 1024) * 64], xc[(size_t)(4*tid + 1026) * 64]);
  float2 zc = make_float2(xc[(size_t)(2047 - 4*tid) * 64], xc[(size_t)(2045 - 4*tid) * 64]);
  float2 zd = make_float2(xc[(size_t)(1023 - 4*tid) * 64], xc[(size_t)(1021 - 4*tid) * 64]);
  __syncthreads();                            // twl visible

  // ---- forward 1024-pt FFT: fused radix-4 L=1 (regs) + 3 LDS stages +
  //      fused last stage (L=256, tb=0, twiddle-free) kept in registers ----
  {
    float2 w1 = twl[tid], w2 = twl[2*tid], w3 = twl[3*tid];
    float2 y0, y1, y2, y3;
    R4REG(za, zb, zc, zd, w1, w2, w3, 1.0f, y0, y1, y2, y3)
    float4* d4 = reinterpret_cast<float4*>(bufA + 4 * tid);
    d4[0] = make_float4(y0.x, y0.y, y1.x, y1.y);
    d4[1] = make_float4(y2.x, y2.y, y3.x, y3.y);
  }
  __syncthreads();
  r4s(bufA, bufB, twl, 1.0f, 3);              // L=4,16,64 -> result in bufB
  float2 Zs0, Zs1, Zs2, Zs3;                  // Z[tid + {0,256,512,768}]
  {
    float2 a = bufB[tid], b2 = bufB[tid + 256];
    float2 c2 = bufB[tid + 512], d2 = bufB[tid + 768];
    float t0x = a.x + c2.x, t0y = a.y + c2.y;
    float t1x = a.x - c2.x, t1y = a.y - c2.y;
    float t2x = b2.x + d2.x, t2y = b2.y + d2.y;
    float t3x = (b2.y - d2.y), t3y = -(b2.x - d2.x);   // fwd -i*(b-d)
    Zs0 = make_float2(t0x + t2x, t0y + t2y);
    Zs1 = make_float2(t1x + t3x, t1y + t3y);
    Zs2 = make_float2(t0x - t2x, t0y - t2y);
    Zs3 = make_float2(t1x - t3x, t1y - t3y);
    bufA[tid]       = Zs0;  bufA[tid + 256] = Zs1;
    bufA[tid + 512] = Zs2;  bufA[tid + 768] = Zs3;
  }
  __syncthreads();

  // ---- unpack: per c, bins (k, 2048-k): R = 2C; own Z from regs ----
  float R0,R1,R2,R3,R4,R5,R6,R7, fj0,fj1,fj2,fj3,fj4,fj5,fj6,fj7;
  #define UNPK(C, ZS, RA, RB, FA, FB) {                        \
    int k = tid + ((C) << 8);                                  \
    float2 Zk = ZS;                                            \
    float2 Zm = bufA[(1024 - k) & 1023];                       \
    float px = 0.5f*(Zk.x + Zm.x), py = 0.5f*(Zk.y - Zm.y);    \
    float qx = 0.5f*(Zk.x - Zm.x), qy = 0.5f*(Zk.y + Zm.y);    \
    float rw = (float)k * (-1.0f / 2048.0f);                   \
    float Wx = __builtin_amdgcn_cosf(rw), Wy = __builtin_amdgcn_sinf(rw); \
    float Vx = px + Wx*qy + Wy*qx;                             \
    float Vy = py - Wx*qx + Wy*qy;                             \
    float re = (float)k * (-1.0f / 8192.0f);                   \
    float Ex = __builtin_amdgcn_cosf(re), Ey = __builtin_amdgcn_sinf(re); \
    RA = 2.0f * (Ex*Vx - Ey*Vy);                               \
    RB = -2.0f * (Ex*Vy + Ey*Vx);                              \
    FA = (float)k * (1.0f/4096.0f);                            \
    FB = (float)(2048 - k) * (1.0f/4096.0f); }
  UNPK(0, Zs0, R0, R1, fj0, fj1)
  UNPK(1, Zs1, R2, R3, fj2, fj3)
  UNPK(2, Zs2, R4, R5, fj4, fj5)
  UNPK(3, Zs3, R6, R7, fj6, fj7)
  if (tid == 0){                              // k=0 pair is (bin0, bin1024)
    R1 = 1.41421356237f * (Zs0.x - Zs0.y);    // sqrt2*V[1024]
    fj1 = 0.25f;
  }

  float4 r0, r1, r2, r3, r4, r5, r6, r7;      // rho[mode] per bin
  float4 om = make_float4(0.0f, 0.125f, 0.25f, 0.375f);

  // iter 1 (rho starts 0) — pure register, real
  {
    float aFP0=0,aFP1=0,aFP2=0,aFP3=0,aP0=0,aP1=0,aP2=0,aP3=0,aD=0;
    FOR8R(IT1R)
    red9(aFP0,aFP1,aFP2,aFP3,aP0,aP1,aP2,aP3,aD, redf, accs + (size_t)g3*16);
  }

  // ---- iters 2..4: tree barrier + replicated-record omega ----
  bool active = true;
  #pragma unroll 1
  for (int it = 0; it < 3; ++it){
    __syncthreads();                          // drain this block's deposits
    if (tid == 0)
      tree_sync_omega(leaf + (size_t)it*64*32, mid + (size_t)it*8*32,
                      root + (size_t)it*32, rec + (size_t)it*8*32,
                      accs + (size_t)it*128, racc + (size_t)it*16,
                      somf, l6, g3);
    __syncthreads();                          // somf visible to all
    if (active){
      if (somf[7] != 0.0f){
        om.x = somf[0]; om.y = somf[1]; om.z = somf[2]; om.w = somf[3];
      } else active = false;
    }
    if (active){
      float aFP0=0,aFP1=0,aFP2=0,aFP3=0,aP0=0,aP1=0,aP2=0,aP3=0,aD=0;
      FOR8R(RBIN)
      red9(aFP0,aFP1,aFP2,aFP3,aP0,aP1,aP2,aP3,aD, redf,
           accs + (size_t)(it + 1)*128 + (size_t)g3*16);
    }
  }
  __syncthreads();
  if (tid == 0)
    tree_sync_omega(leaf + (size_t)3*64*32, mid + (size_t)3*8*32,
                    root + (size_t)3*32, rec + (size_t)3*8*32,
                    accs + (size_t)3*128, racc + (size_t)3*16,
                    somf, l6, g3);
  __syncthreads();

  // ---- iter-5 mode-0 (real) -> c values; V' -> bufA; packed IFFT ----
  {
    bool act = active && (somf[7] != 0.0f);
    float om0 = somf[0];
    float c0, c1, c2, c3, c4, c5, c6, c7;
    C5(r0, R0, fj0, c0)  C5(r1, R1, fj1, c1)
    C5(r2, R2, fj2, c2)  C5(r3, R3, fj3, c3)
    C5(r4, R4, fj4, c4)  C5(r5, R5, fj5, c5)
    C5(r6, R6, fj6, c6)  C5(r7, R7, fj7, c7)
    if (tid == 1) sKs = c1;                   // bin 2047 (pair of k=1)
    if (tid == 0) vNy = make_float2(1.41421356237f * c1, 0.0f); // V'[1024]
    // V'[k] = e^{+i pi k/4096} (c_k - i c_{2048-k})
    #define VPW(C, CA, CB) {                                   \
      int k = tid + ((C) << 8);                                \
      float rg = (float)k * (1.0f / 8192.0f);                  \
      float Gx = __builtin_amdgcn_cosf(rg), Gy = __builtin_amdgcn_sinf(rg); \
      bufA[k] = make_float2(Gx*(CA) + Gy*(CB), Gy*(CA) - Gx*(CB)); }
    VPW(0, c0, c1)  VPW(1, c2, c3)  VPW(2, c4, c5)  VPW(3, c6, c7)
    if (tid == 0) bufA[0] = make_float2(c0, 0.0f);   // V'[0] = c_0 (real)
  }
  __syncthreads();
  // Z''[q] = E + iO; E = V'[q]+conj(V'[1024-q]); O = (V'[q]-conj(V'[1024-q]))*W
  float2 p0, p1, p2, p3;
  #define ZB(C, ZV) {                                          \
    int q = tid + ((C) << 8);                                  \
    float2 Vq = bufA[q];                                       \
    float2 Vm = (q == 0) ? vNy : bufA[1024 - q];               \
    Vm.y = -Vm.y;                                              \
    float Ex_ = Vq.x + Vm.x, Ey_ = Vq.y + Vm.y;                \
    float Dx = Vq.x - Vm.x,  Dy = Vq.y - Vm.y;                 \
    float rw = (float)q * (1.0f / 2048.0f);                    \
    float Wx = __builtin_amdgcn_cosf(rw), Wy = __builtin_amdgcn_sinf(rw); \
    float Ox = Dx*Wx - Dy*Wy;                                  \
    float Oy = Dx*Wy + Dy*Wx;                                  \
    ZV = make_float2(Ex_ - Oy, Ey_ + Ox); }
  ZB(0, p0)  ZB(1, p1)  ZB(2, p2)  ZB(3, p3)
  {                                           // fused inverse radix-4 L=1
    float2 w1 = twl[tid], w2 = twl[2*tid], w3 = twl[3*tid];
    float2 y0, y1, y2, y3;
    R4REG(p0, p1, p2, p3, w1, w2, w3, -1.0f, y0, y1, y2, y3)
    float4* d4 = reinterpret_cast<float4*>(bufB + 4 * tid);
    d4[0] = make_float4(y0.x, y0.y, y1.x, y1.y);
    d4[1] = make_float4(y2.x, y2.y, y3.x, y3.y);
  }
  __syncthreads();
  r4s(bufB, bufA, twl, -1.0f, 3);             // L=4,16,64 -> result in bufA

  // ---- fused last inverse stage (L=256, tb=0, twiddle-free) + epilogue ----
  {
    float2 a = bufA[tid], bb = bufA[tid + 256];
    float2 c = bufA[tid + 512], d = bufA[tid + 768];
    float t0x = a.x + c.x, t0y = a.y + c.y;
    float t1x = a.x - c.x, t1y = a.y - c.y;
    float t2x = bb.x + d.x, t2y = bb.y + d.y;
    float t3x = -(bb.y - d.y), t3y = (bb.x - d.x);   // sgn=-1
    float2 y0 = make_float2(t0x + t2x, t0y + t2y);   // z''[tid]
    float2 y1 = make_float2(t1x + t3x, t1y + t3y);   // z''[tid+256]
    float2 y2 = make_float2(t0x - t2x, t0y - t2y);   // z''[tid+512]
    float2 y3 = make_float2(t1x - t3x, t1y - t3y);   // z''[tid+768]
    const float sc = 1.0f / 4096.0f;
    float kc = sKs * (0.99999970586f * sc);   // rho_2047*cos(pi/4096)/4096
    // x_l[t] = Re(z'')/4096 - (-1)^t * kc
    #define OUT2(YV, T0, T1, KS, ZS) {                         \
      size_t oa = ((size_t)(b * 2048 + (T0))) * 64 + ch;       \
      size_t ob = ((size_t)(b * 2048 + (T1))) * 64 + ch;       \
      float l0 = YV.x * sc KS kc;                              \
      float l1 = YV.y * sc KS kc;                              \
      xl[oa] = l0;  xh[oa] = ZS.x - l0;                        \
      xl[ob] = l1;  xh[ob] = ZS.y - l1; }
    OUT2(y0, 4*tid,        4*tid + 2,    -, za)      // even t
    OUT2(y1, 4*tid + 1024, 4*tid + 1026, -, zb)      // even t
    OUT2(y2, 2047 - 4*tid, 2045 - 4*tid, +, zc)      // odd t
    OUT2(y3, 1023 - 4*tid, 1021 - 4*tid, +, zd)      // odd t
  }
}

extern "C" void kernel_launch(void* const* d_in, const int* in_sizes, int n_in,
                              void* d_out, int out_size, void* d_ws, size_t ws_size,
                              hipStream_t stream){
  const float* x = (const float*)d_in[0];
  float* out_xh = (float*)d_out;
  float* out_xl = out_xh + (size_t)8 * 2048 * 64;

  // ws layout (all zeroed each launch; strides of 128 B per line):
  //   leaf: 4 rounds x 64 x 128B = 32768 @ 0
  //   mid:  4 x 8 x 128B         =  4096 @ 32768
  //   root: 4 x 128B             =   512 @ 36864
  //   racc: 4 x 128B (9 dbl)     =   512 @ 37376
  //   rec:  4 x 8 x 128B         =  4096 @ 37888
  //   accs: 4 x 8 x 128B         =  4096 @ 41984
  char* ws = (char*)d_ws;
  unsigned* leaf = (unsigned*)ws;
  unsigned* mid  = (unsigned*)(ws + 32768);
  unsigned* root = (unsigned*)(ws + 36864);
  double*   racc = (double*)  (ws + 37376);
  unsigned* rec  = (unsigned*)(ws + 37888);
  double*   accs = (double*)  (ws + 41984);

  hipMemsetAsync(ws, 0, 46080, stream);
  k_main<<<NBLK, 256, 0, stream>>>(x, leaf, mid, root, rec, racc, accs,
                                   out_xh, out_xl);
}